// Round 7
// baseline (235.770 us; speedup 1.0000x reference)
//
#include <hip/hip_runtime.h>
#include <hip/hip_bf16.h>
#include <stdint.h>

// Problem constants
#define B_ 2
#define T_ 2048
#define C_ 1024
#define H_ 16
#define D_ 64

typedef __attribute__((ext_vector_type(8))) short bf16x8;
typedef __attribute__((ext_vector_type(4))) float f32x4;

__device__ __forceinline__ unsigned short f2bf(float f) {
  union { float f; uint32_t u; } c; c.f = f;
  uint32_t r = c.u + 0x7FFFu + ((c.u >> 16) & 1u);  // RNE
  return (unsigned short)(r >> 16);
}

// v_cvt_pk_bf16_f32: D[15:0]=bf16(lo), D[31:16]=bf16(hi), RNE
__device__ __forceinline__ uint32_t pack_bf16x2(float lo, float hi) {
  uint32_t r;
  asm("v_cvt_pk_bf16_f32 %0, %1, %2" : "=v"(r) : "v"(lo), "v"(hi));
  return r;
}

// async global->LDS, 16B per lane; LDS dest = uniform base + lane*16 (linear)
__device__ __forceinline__ void gload_lds16(const unsigned short* g,
                                            unsigned short* l) {
  __builtin_amdgcn_global_load_lds(
      (const __attribute__((address_space(1))) void*)(g),
      (__attribute__((address_space(3))) void*)(l), 16, 0, 0);
}

// ---------------------------------------------------------------- cvt f32->bf16
// one launch converts x, Wqkv, Wproj (2.10M float4s total)
#define N4_X 1048576
#define N4_WQ 786432
#define N4_WP 262144
__global__ void cvt_all(const float* __restrict__ x,
                        const float* __restrict__ wqkv,
                        const float* __restrict__ wproj,
                        unsigned short* __restrict__ xb,
                        unsigned short* __restrict__ wq,
                        unsigned short* __restrict__ wp) {
  int i = blockIdx.x * 256 + threadIdx.x;
  const float* s; unsigned short* d; int j;
  if (i < N4_X) { s = x; d = xb; j = i; }
  else if (i < N4_X + N4_WQ) { s = wqkv; d = wq; j = i - N4_X; }
  else { s = wproj; d = wp; j = i - (N4_X + N4_WQ); }
  float4 v = ((const float4*)s)[j];
  ushort4 o;
  o.x = f2bf(v.x); o.y = f2bf(v.y); o.z = f2bf(v.z); o.w = f2bf(v.w);
  ((ushort4*)d)[j] = o;
}

// ---------------------------------------------------------------- mask lengths
__global__ void compute_lengths(const unsigned int* __restrict__ mask,
                                int* __restrict__ lens) {
  int lane = threadIdx.x;
  unsigned int w0 = mask[0];
  for (int b = 0; b < B_; ++b) {
    int cnt = 0;
    if (w0 == 1u) {
      for (int t = lane; t < T_; t += 64) cnt += (mask[(size_t)b * T_ + t] != 0u);
    } else if (w0 == 0x3F800000u) {
      const float* mf = (const float*)mask;
      for (int t = lane; t < T_; t += 64) cnt += (mf[(size_t)b * T_ + t] != 0.f);
    } else {
      const unsigned char* mb = (const unsigned char*)mask;
      for (int t = lane; t < T_; t += 64) cnt += (mb[(size_t)b * T_ + t] != 0);
    }
    for (int off = 32; off > 0; off >>= 1) cnt += __shfl_down(cnt, off);
    if (lane == 0) lens[b] = cnt;
  }
}

// ---------------------------------------------------------------- GEMM (bt form)
// out[m][n] = sum_k A[m][k] * Bm[n][k] + bias[n]
// mode 0: scatter epilogue to Q/K/V (B,H,T,D) bf16 (Q scaled by log2e/8)
// mode 1: fp32 output to outF (row-major M x N)
// Staging: global_load_lds width-16, linear LDS dest, source pre-swizzled:
//   LDS chunk (row, cc) holds logical k-chunk cc^(row&7)  (T2 swizzle)
__global__ __launch_bounds__(256)
void gemm_bt(const unsigned short* __restrict__ A,
             const unsigned short* __restrict__ Bm,
             const float* __restrict__ bias,
             float* __restrict__ outF,
             unsigned short* __restrict__ Qw,
             unsigned short* __restrict__ Kw,
             unsigned short* __restrict__ Vw,
             int N, int K, int mode) {
  __shared__ unsigned short As[128 * 64];
  __shared__ unsigned short Bs[128 * 64];
  const int tid = threadIdx.x;
  const int lane = tid & 63;
  const int w = tid >> 6;
  const int wm = w >> 1, wn = w & 1;
  const int q4 = lane >> 4, l15 = lane & 15;
  const int bm = blockIdx.y * 128;
  const int bn = blockIdx.x * 128;

  f32x4 acc[4][4] = {};

  for (int kt = 0; kt < K; kt += 64) {
    // wave w stages rows w*32 .. w*32+31 of A and B (8 rows / call)
#pragma unroll
    for (int i = 0; i < 4; ++i) {
      int r0 = w * 32 + i * 8;
      int row = r0 + (lane >> 3);
      int kc = (lane & 7) ^ (row & 7);
      gload_lds16(A + (size_t)(bm + row) * K + kt + kc * 8, &As[r0 * 64]);
      gload_lds16(Bm + (size_t)(bn + row) * K + kt + kc * 8, &Bs[r0 * 64]);
    }
    __syncthreads();
#pragma unroll
    for (int kk = 0; kk < 2; ++kk) {
      bf16x8 af[4], bfv[4];
#pragma unroll
      for (int mi = 0; mi < 4; ++mi) {
        int row = wm * 64 + mi * 16 + l15;
        int pc = (kk * 4 + q4) ^ (row & 7);
        af[mi] = *(const bf16x8*)(As + (size_t)row * 64 + pc * 8);
      }
#pragma unroll
      for (int ni = 0; ni < 4; ++ni) {
        int row = wn * 64 + ni * 16 + l15;
        int pc = (kk * 4 + q4) ^ (row & 7);
        bfv[ni] = *(const bf16x8*)(Bs + (size_t)row * 64 + pc * 8);
      }
#pragma unroll
      for (int mi = 0; mi < 4; ++mi)
#pragma unroll
        for (int ni = 0; ni < 4; ++ni)
          acc[mi][ni] = __builtin_amdgcn_mfma_f32_16x16x32_bf16(
              af[mi], bfv[ni], acc[mi][ni], 0, 0, 0);
    }
    __syncthreads();
  }

  // epilogue; C/D frag: col = lane&15, row = (lane>>4)*4 + reg  [m89/m91]
#pragma unroll
  for (int mi = 0; mi < 4; ++mi) {
    const int row0 = bm + wm * 64 + mi * 16 + q4 * 4;
#pragma unroll
    for (int ni = 0; ni < 4; ++ni) {
      const int col = bn + wn * 64 + ni * 16 + l15;
      const float bv = bias[col];
#pragma unroll
      for (int r = 0; r < 4; ++r) {
        const int row = row0 + r;
        float v = acc[mi][ni][r] + bv;
        if (mode == 1) {
          outF[(size_t)row * N + col] = v;
        } else {
          int b = row >> 11, t = row & (T_ - 1);
          int which = col >> 10, c = col & (C_ - 1);
          int h = c >> 6, dd = c & (D_ - 1);
          unsigned short* dst = (which == 0) ? Qw : ((which == 1) ? Kw : Vw);
          // fold softmax scale AND log2(e) into Q (attention uses exp2)
          if (which == 0) v *= 0.1803368801111243f;  // 0.125 * log2(e)
          dst[(((size_t)(b * H_ + h) * T_) + t) * D_ + dd] = f2bf(v);
        }
      }
    }
  }
}

// ---------------------------------------------------------------- V transpose
__global__ __launch_bounds__(256)
void transpose_v(const unsigned short* __restrict__ V,
                 unsigned short* __restrict__ Vt) {
  __shared__ unsigned short tile[64][65];
  int bh = blockIdx.y;
  int t0 = blockIdx.x * 64;
  int tid = threadIdx.x;
  int r = tid >> 2, c0 = (tid & 3) * 16;
  const uint4* s4 = (const uint4*)(V + ((size_t)bh * T_ + t0 + r) * D_ + c0);
  union { uint4 v; unsigned short u[8]; } ua, ub;
  ua.v = s4[0]; ub.v = s4[1];
#pragma unroll
  for (int j = 0; j < 8; ++j) {
    tile[r][c0 + j] = ua.u[j];
    tile[r][c0 + 8 + j] = ub.u[j];
  }
  __syncthreads();
  int dd = tid >> 2, tt0 = (tid & 3) * 16;
  union { uint4 v[2]; unsigned short u[16]; } ov;
#pragma unroll
  for (int j = 0; j < 16; ++j) ov.u[j] = tile[tt0 + j][dd];
  uint4* dptr = (uint4*)(Vt + ((size_t)bh * D_ + dd) * T_ + t0 + tt0);
  dptr[0] = ov.v[0];
  dptr[1] = ov.v[1];
}

// ---------------------------------------------------------------- attention
// 4 waves/block, wave owns 16 q-rows, 64-row q-strips, KV tiles of 64.
// Load-balance rationale (R6 counters): block cost ~ strip index (1..32 KV
// tiles); 1024 small blocks dispatched heavy-first give near-LPT greedy
// balance and dynamic CU refill (R6's 128-row / 512-block version idled
// ~57% of wave-slots in the causal tail). LDS 40KB -> 4 blocks/CU = 50%
// static occupancy.
// Swapped-operand: S^T = mfma(K,Q), lane l15 = q-row, per-lane softmax stats;
// P packed via v_cvt_pk_bf16_f32, b64 writes to per-wave LDS; O^T = mfma(Vt,Pt).
// K/V staged by global_load_lds (dbuf, 1 barrier/tile). Q pre-scaled by
// 0.125*log2e; exp2 domain; defer-max THR=8; interior tiles skip mask VALU.
__global__ __launch_bounds__(256)
void attn_fwd(const unsigned short* __restrict__ Qw,
              const unsigned short* __restrict__ Kw,
              const unsigned short* __restrict__ Vt,
              unsigned short* __restrict__ AO,
              const int* __restrict__ lens) {
  __shared__ unsigned short Ks[2][64 * 64];   // [key 64][d 64] chunk-swizzled
  __shared__ unsigned short Vs[2][64 * 64];   // [d 64][key 64] chunk-swizzled
  __shared__ unsigned short Pb[4][16 * 64];   // per-wave P [q 16][k 64]

  const int bh = blockIdx.y;
  const int b = bh >> 4;
  const int h = bh & 15;
  const int qs = 31 - blockIdx.x;              // heavy strips dispatch first
  const int q0 = qs * 64;
  const int tid = threadIdx.x;
  const int lane = tid & 63;
  const int w = tid >> 6;                      // 0..3
  const int q4 = lane >> 4, l15 = lane & 15;
  const int len = lens[b];

  const unsigned short* Qp = Qw + (size_t)bh * T_ * D_;
  const unsigned short* Kp = Kw + (size_t)bh * T_ * D_;
  const unsigned short* Vp = Vt + (size_t)bh * D_ * T_;
  unsigned short* Pw = &Pb[w][0];

  const int qw0 = q0 + w * 16;        // this wave's 16 q-rows
  const int qwmax = qw0 + 15;

  // Q fragments (B-operand for swapped QK^T): lane l15 = q-row
  bf16x8 qf[2];
#pragma unroll
  for (int kk = 0; kk < 2; ++kk)
    qf[kk] = *(const bf16x8*)(Qp + (size_t)(qw0 + l15) * D_ + kk * 32 + q4 * 8);

  f32x4 ot[4] = {};                 // O^T accum: [dt], lane l15=q, row=d
  float m = -INFINITY;              // per-lane (q-row) stats
  float lsum = 0.f;

  int kcap = q0 + 63;
  if (kcap > len - 1) kcap = len - 1;
  const int nkt = kcap / 64 + 1;

  // staging: wave w stages rows w*16..w*16+15 of K and V tiles (2 calls each)
  const int srow = lane >> 3;   // 0..7
  const int scc = lane & 7;

  // prologue: stage tile 0 into buf 0
#pragma unroll
  for (int i = 0; i < 2; ++i) {
    int r0 = w * 16 + i * 8;
    int rk = r0 + srow;
    int kc = scc ^ (rk & 7);
    gload_lds16(Kp + (size_t)rk * D_ + kc * 8, &Ks[0][r0 * 64]);
    gload_lds16(Vp + (size_t)rk * T_ + kc * 8, &Vs[0][r0 * 64]);
  }
  __syncthreads();

  int cur = 0;
  for (int kt = 0; kt < nkt; ++kt) {
    const int kbase = kt * 64;
    // prefetch next tile into back buffer (in flight during compute)
    if (kt + 1 < nkt) {
      const int kb2 = kbase + 64;
#pragma unroll
      for (int i = 0; i < 2; ++i) {
        int r0 = w * 16 + i * 8;
        int rk = r0 + srow;
        int kc = scc ^ (rk & 7);
        gload_lds16(Kp + (size_t)(kb2 + rk) * D_ + kc * 8, &Ks[cur ^ 1][r0 * 64]);
        gload_lds16(Vp + (size_t)rk * T_ + kb2 + kc * 8, &Vs[cur ^ 1][r0 * 64]);
      }
    }

    if (kbase <= qwmax) {
      // ---- S^T = K Q^T : st[nt], lane: col=q=l15, row=k=nt*16+q4*4+r
      f32x4 st[4];
#pragma unroll
      for (int nt = 0; nt < 4; ++nt) {
        bf16x8 kfr0, kfr1;
        {
          int row = nt * 16 + l15;
          int pc0 = q4 ^ (row & 7);
          int pc1 = (4 + q4) ^ (row & 7);
          kfr0 = *(const bf16x8*)(&Ks[cur][row * 64 + pc0 * 8]);
          kfr1 = *(const bf16x8*)(&Ks[cur][row * 64 + pc1 * 8]);
        }
        f32x4 z = {};
        z = __builtin_amdgcn_mfma_f32_16x16x32_bf16(kfr0, qf[0], z, 0, 0, 0);
        z = __builtin_amdgcn_mfma_f32_16x16x32_bf16(kfr1, qf[1], z, 0, 0, 0);
        st[nt] = z;
      }
      // ---- mask + per-row (per-lane) max
      const bool interior = (kbase + 63 <= qw0) && (kbase + 63 < len);
      float pmax = -INFINITY;
      if (interior) {
#pragma unroll
        for (int nt = 0; nt < 4; ++nt)
#pragma unroll
          for (int r = 0; r < 4; ++r) pmax = fmaxf(pmax, st[nt][r]);
      } else {
        const int qq = qw0 + l15;
#pragma unroll
        for (int nt = 0; nt < 4; ++nt)
#pragma unroll
          for (int r = 0; r < 4; ++r) {
            int kpos = kbase + nt * 16 + q4 * 4 + r;
            bool ok = (kpos < len) && (kpos <= qq);
            float v = ok ? st[nt][r] : -INFINITY;
            st[nt][r] = v;
            pmax = fmaxf(pmax, v);
          }
      }
      pmax = fmaxf(pmax, __shfl_xor(pmax, 16));
      pmax = fmaxf(pmax, __shfl_xor(pmax, 32));
      // ---- defer-max rescale (THR=8 in log2 domain)
      if (!__all(pmax <= m + 8.f)) {
        float mn = fmaxf(m, pmax);
        float sc = exp2f(m - mn);
        m = mn;
        lsum *= sc;
#pragma unroll
        for (int dt = 0; dt < 4; ++dt)
#pragma unroll
          for (int r = 0; r < 4; ++r) ot[dt][r] *= sc;
      }
      // ---- P = exp2(S - m): pack pairs, accumulate psum, write b64 to LDS
      float psum = 0.f;
#pragma unroll
      for (int nt = 0; nt < 4; ++nt) {
        float p0 = exp2f(st[nt][0] - m);
        float p1 = exp2f(st[nt][1] - m);
        float p2 = exp2f(st[nt][2] - m);
        float p3 = exp2f(st[nt][3] - m);
        psum += (p0 + p1) + (p2 + p3);
        uint32_t w0 = pack_bf16x2(p0, p1);
        uint32_t w1 = pack_bf16x2(p2, p3);
        int c = nt * 4 + q4;                    // 8B chunk (4 bf16), k=c*4
        int phys = c ^ ((l15 & 7) << 1);        // keeps pairs adjacent
        uint2 pr; pr.x = w0; pr.y = w1;
        *(uint2*)(&Pw[l15 * 64 + phys * 4]) = pr;
      }
      psum += __shfl_xor(psum, 16);
      psum += __shfl_xor(psum, 32);
      lsum += psum;
      // ---- PV: O^T += V^T P^T ; A=vfr (V^T, shared LDS), B=pt (P^T)
      bf16x8 pt[2];
#pragma unroll
      for (int kk = 0; kk < 2; ++kk) {
        int c0 = kk * 8 + q4 * 2;               // even chunk, b128 = 2 chunks
        int phys = c0 ^ ((l15 & 7) << 1);
        pt[kk] = *(const bf16x8*)(&Pw[l15 * 64 + phys * 4]);
      }
#pragma unroll
      for (int dt = 0; dt < 4; ++dt) {
        bf16x8 vfr0, vfr1;
        {
          int row = dt * 16 + l15;
          int pc0 = q4 ^ (row & 7);
          int pc1 = (4 + q4) ^ (row & 7);
          vfr0 = *(const bf16x8*)(&Vs[cur][row * 64 + pc0 * 8]);
          vfr1 = *(const bf16x8*)(&Vs[cur][row * 64 + pc1 * 8]);
        }
        ot[dt] = __builtin_amdgcn_mfma_f32_16x16x32_bf16(vfr0, pt[0], ot[dt], 0, 0, 0);
        ot[dt] = __builtin_amdgcn_mfma_f32_16x16x32_bf16(vfr1, pt[1], ot[dt], 0, 0, 0);
      }
    }

    __syncthreads();   // drains prefetch (vmcnt0) + guards buffer reuse
    cur ^= 1;
  }

  // epilogue: O^T frag -> lane l15=q, d = dt*16 + q4*4 + r (4 consecutive)
  {
    float inv = 1.f / lsum;
    int qq = qw0 + l15;
#pragma unroll
    for (int dt = 0; dt < 4; ++dt) {
      uint2 pr;
      pr.x = pack_bf16x2(ot[dt][0] * inv, ot[dt][1] * inv);
      pr.y = pack_bf16x2(ot[dt][2] * inv, ot[dt][3] * inv);
      *(uint2*)(&AO[(size_t)(b * T_ + qq) * C_ + h * 64 + dt * 16 + q4 * 4]) = pr;
    }
  }
}

// ---------------------------------------------------------------- launch
extern "C" void kernel_launch(void* const* d_in, const int* in_sizes, int n_in,
                              void* d_out, int out_size, void* d_ws, size_t ws_size,
                              hipStream_t stream) {
  const float* x = (const float*)d_in[0];
  const unsigned int* mask = (const unsigned int*)d_in[1];
  const float* Wqkv = (const float*)d_in[2];
  const float* bqkv = (const float*)d_in[3];
  const float* Wproj = (const float*)d_in[4];
  const float* bproj = (const float*)d_in[5];
  float* out = (float*)d_out;

  unsigned short* XB = (unsigned short*)d_ws;       // x bf16       (4096x1024)
  unsigned short* WQ = XB + 4194304;                // Wqkv bf16    (3072x1024)
  unsigned short* WP = WQ + 3145728;                // Wproj bf16   (1024x1024)
  unsigned short* Qw = WP + 1048576;                // (B,H,T,D)
  unsigned short* Kw = Qw + 4194304;
  unsigned short* Vw = Kw + 4194304;
  unsigned short* Vt = Vw + 4194304;                // (B,H,D,T)
  unsigned short* AO = Vt + 4194304;                // attn out (B,T,C) bf16
  int* lens = (int*)(AO + 4194304);

  cvt_all<<<8192, 256, 0, stream>>>(x, Wqkv, Wproj, XB, WQ, WP);
  compute_lengths<<<1, 64, 0, stream>>>(mask, lens);

  // QKV projection: M=4096, N=3072, K=1024, scatter epilogue
  gemm_bt<<<dim3(3072 / 128, 4096 / 128), 256, 0, stream>>>(
      XB, WQ, bqkv, nullptr, Qw, Kw, Vw, 3072, 1024, 0);

  transpose_v<<<dim3(T_ / 64, B_ * H_), 256, 0, stream>>>(Vw, Vt);

  attn_fwd<<<dim3(32, B_ * H_), 256, 0, stream>>>(Qw, Kw, Vt, AO, lens);

  // output projection: M=4096, N=1024, K=1024, fp32 out
  gemm_bt<<<dim3(1024 / 128, 4096 / 128), 256, 0, stream>>>(
      AO, WP, bproj, out, nullptr, nullptr, nullptr, 1024, 1024, 1);
}

// Round 9
// 216.756 us; speedup vs baseline: 1.0877x; 1.0877x over previous
//
#include <hip/hip_runtime.h>
#include <hip/hip_bf16.h>
#include <stdint.h>

// Problem constants
#define B_ 2
#define T_ 2048
#define C_ 1024
#define H_ 16
#define D_ 64

typedef __attribute__((ext_vector_type(8))) short bf16x8;
typedef __attribute__((ext_vector_type(4))) float f32x4;

__device__ __forceinline__ unsigned short f2bf(float f) {
  union { float f; uint32_t u; } c; c.f = f;
  uint32_t r = c.u + 0x7FFFu + ((c.u >> 16) & 1u);  // RNE
  return (unsigned short)(r >> 16);
}

// v_cvt_pk_bf16_f32: D[15:0]=bf16(lo), D[31:16]=bf16(hi), RNE
__device__ __forceinline__ uint32_t pack_bf16x2(float lo, float hi) {
  uint32_t r;
  asm("v_cvt_pk_bf16_f32 %0, %1, %2" : "=v"(r) : "v"(lo), "v"(hi));
  return r;
}

// async global->LDS, 16B per lane; LDS dest = uniform base + lane*16 (linear)
__device__ __forceinline__ void gload_lds16(const unsigned short* g,
                                            unsigned short* l) {
  __builtin_amdgcn_global_load_lds(
      (const __attribute__((address_space(1))) void*)(g),
      (__attribute__((address_space(3))) void*)(l), 16, 0, 0);
}

// ---------------------------------------------------------------- cvt f32->bf16
// one launch converts x, Wqkv, Wproj (2.10M float4s total)
#define N4_X 1048576
#define N4_WQ 786432
#define N4_WP 262144
__global__ void cvt_all(const float* __restrict__ x,
                        const float* __restrict__ wqkv,
                        const float* __restrict__ wproj,
                        unsigned short* __restrict__ xb,
                        unsigned short* __restrict__ wq,
                        unsigned short* __restrict__ wp) {
  int i = blockIdx.x * 256 + threadIdx.x;
  const float* s; unsigned short* d; int j;
  if (i < N4_X) { s = x; d = xb; j = i; }
  else if (i < N4_X + N4_WQ) { s = wqkv; d = wq; j = i - N4_X; }
  else { s = wproj; d = wp; j = i - (N4_X + N4_WQ); }
  float4 v = ((const float4*)s)[j];
  ushort4 o;
  o.x = f2bf(v.x); o.y = f2bf(v.y); o.z = f2bf(v.z); o.w = f2bf(v.w);
  ((ushort4*)d)[j] = o;
}

// ---------------------------------------------------------------- mask lengths
__global__ void compute_lengths(const unsigned int* __restrict__ mask,
                                int* __restrict__ lens) {
  int lane = threadIdx.x;
  unsigned int w0 = mask[0];
  for (int b = 0; b < B_; ++b) {
    int cnt = 0;
    if (w0 == 1u) {
      for (int t = lane; t < T_; t += 64) cnt += (mask[(size_t)b * T_ + t] != 0u);
    } else if (w0 == 0x3F800000u) {
      const float* mf = (const float*)mask;
      for (int t = lane; t < T_; t += 64) cnt += (mf[(size_t)b * T_ + t] != 0.f);
    } else {
      const unsigned char* mb = (const unsigned char*)mask;
      for (int t = lane; t < T_; t += 64) cnt += (mb[(size_t)b * T_ + t] != 0);
    }
    for (int off = 32; off > 0; off >>= 1) cnt += __shfl_down(cnt, off);
    if (lane == 0) lens[b] = cnt;
  }
}

// ---------------------------------------------------------------- GEMM (bt form)
// out[m][n] = sum_k A[m][k] * Bm[n][k] + bias[n]
// mode 0: scatter epilogue to Q/K/V (B,H,T,D) bf16 (Q scaled by log2e/8)
// mode 1: fp32 output to outF (row-major M x N)
__global__ __launch_bounds__(256)
void gemm_bt(const unsigned short* __restrict__ A,
             const unsigned short* __restrict__ Bm,
             const float* __restrict__ bias,
             float* __restrict__ outF,
             unsigned short* __restrict__ Qw,
             unsigned short* __restrict__ Kw,
             unsigned short* __restrict__ Vw,
             int N, int K, int mode) {
  __shared__ unsigned short As[128 * 64];
  __shared__ unsigned short Bs[128 * 64];
  const int tid = threadIdx.x;
  const int lane = tid & 63;
  const int w = tid >> 6;
  const int wm = w >> 1, wn = w & 1;
  const int q4 = lane >> 4, l15 = lane & 15;
  const int bm = blockIdx.y * 128;
  const int bn = blockIdx.x * 128;

  f32x4 acc[4][4] = {};

  for (int kt = 0; kt < K; kt += 64) {
    // wave w stages rows w*32 .. w*32+31 of A and B (8 rows / call)
#pragma unroll
    for (int i = 0; i < 4; ++i) {
      int r0 = w * 32 + i * 8;
      int row = r0 + (lane >> 3);
      int kc = (lane & 7) ^ (row & 7);
      gload_lds16(A + (size_t)(bm + row) * K + kt + kc * 8, &As[r0 * 64]);
      gload_lds16(Bm + (size_t)(bn + row) * K + kt + kc * 8, &Bs[r0 * 64]);
    }
    __syncthreads();
#pragma unroll
    for (int kk = 0; kk < 2; ++kk) {
      bf16x8 af[4], bfv[4];
#pragma unroll
      for (int mi = 0; mi < 4; ++mi) {
        int row = wm * 64 + mi * 16 + l15;
        int pc = (kk * 4 + q4) ^ (row & 7);
        af[mi] = *(const bf16x8*)(As + (size_t)row * 64 + pc * 8);
      }
#pragma unroll
      for (int ni = 0; ni < 4; ++ni) {
        int row = wn * 64 + ni * 16 + l15;
        int pc = (kk * 4 + q4) ^ (row & 7);
        bfv[ni] = *(const bf16x8*)(Bs + (size_t)row * 64 + pc * 8);
      }
#pragma unroll
      for (int mi = 0; mi < 4; ++mi)
#pragma unroll
        for (int ni = 0; ni < 4; ++ni)
          acc[mi][ni] = __builtin_amdgcn_mfma_f32_16x16x32_bf16(
              af[mi], bfv[ni], acc[mi][ni], 0, 0, 0);
    }
    __syncthreads();
  }

  // epilogue; C/D frag: col = lane&15, row = (lane>>4)*4 + reg  [m89/m91]
#pragma unroll
  for (int mi = 0; mi < 4; ++mi) {
    const int row0 = bm + wm * 64 + mi * 16 + q4 * 4;
#pragma unroll
    for (int ni = 0; ni < 4; ++ni) {
      const int col = bn + wn * 64 + ni * 16 + l15;
      const float bv = bias[col];
#pragma unroll
      for (int r = 0; r < 4; ++r) {
        const int row = row0 + r;
        float v = acc[mi][ni][r] + bv;
        if (mode == 1) {
          outF[(size_t)row * N + col] = v;
        } else {
          int b = row >> 11, t = row & (T_ - 1);
          int which = col >> 10, c = col & (C_ - 1);
          int h = c >> 6, dd = c & (D_ - 1);
          unsigned short* dst = (which == 0) ? Qw : ((which == 1) ? Kw : Vw);
          // fold softmax scale AND log2(e) into Q (attention uses exp2)
          if (which == 0) v *= 0.1803368801111243f;  // 0.125 * log2(e)
          dst[(((size_t)(b * H_ + h) * T_) + t) * D_ + dd] = f2bf(v);
        }
      }
    }
  }
}

// ---------------------------------------------------------------- V transpose
__global__ __launch_bounds__(256)
void transpose_v(const unsigned short* __restrict__ V,
                 unsigned short* __restrict__ Vt) {
  __shared__ unsigned short tile[64][65];
  int bh = blockIdx.y;
  int t0 = blockIdx.x * 64;
  int tid = threadIdx.x;
  int r = tid >> 2, c0 = (tid & 3) * 16;
  const uint4* s4 = (const uint4*)(V + ((size_t)bh * T_ + t0 + r) * D_ + c0);
  union { uint4 v; unsigned short u[8]; } ua, ub;
  ua.v = s4[0]; ub.v = s4[1];
#pragma unroll
  for (int j = 0; j < 8; ++j) {
    tile[r][c0 + j] = ua.u[j];
    tile[r][c0 + 8 + j] = ub.u[j];
  }
  __syncthreads();
  int dd = tid >> 2, tt0 = (tid & 3) * 16;
  union { uint4 v[2]; unsigned short u[16]; } ov;
#pragma unroll
  for (int j = 0; j < 16; ++j) ov.u[j] = tile[tt0 + j][dd];
  uint4* dptr = (uint4*)(Vt + ((size_t)bh * D_ + dd) * T_ + t0 + tt0);
  dptr[0] = ov.v[0];
  dptr[1] = ov.v[1];
}

// ---------------------------------------------------------------- attention
// COMPLEMENTARY-STRIP PAIRING (load balance independent of dispatch):
// block (p, bh) handles q-strip p AND strip 31-p; per-wave work =
// (p+1) + (32-p) = 33 KV-tile-units, identical for ALL 512 blocks (2/CU).
// R7 lesson: CU i received 4 same-cost blocks (lin+256 preserved blockIdx.x)
// -> 32:1 per-CU skew; pairing makes per-CU cost uniform by construction.
// Wave owns 16 q-rows in each strip; K/V staging (high strip's tile range,
// superset of low's) shared by all 4 waves; dbuf global_load_lds.
// Swapped-operand: S^T = mfma(K,Q), lane l15 = q-row, per-lane softmax stats;
// P packed via v_cvt_pk_bf16_f32, b64 writes to per-wave LDS; O^T = mfma(Vt,Pt).
// Q pre-scaled by 0.125*log2e; exp2 domain; defer-max THR=8.
__global__ __launch_bounds__(256)
void attn_fwd(const unsigned short* __restrict__ Qw,
              const unsigned short* __restrict__ Kw,
              const unsigned short* __restrict__ Vt,
              unsigned short* __restrict__ AO,
              const int* __restrict__ lens) {
  __shared__ unsigned short Ks[2][64 * 64];   // [key 64][d 64] chunk-swizzled
  __shared__ unsigned short Vs[2][64 * 64];   // [d 64][key 64] chunk-swizzled
  __shared__ unsigned short Pb[4][16 * 64];   // per-wave P [q 16][k 64]

  const int bh = blockIdx.y;
  const int b = bh >> 4;
  const int h = bh & 15;
  const int sl = blockIdx.x;                   // low strip 0..15
  const int sh = 31 - sl;                      // high strip 31..16
  const int tid = threadIdx.x;
  const int lane = tid & 63;
  const int w = tid >> 6;                      // 0..3
  const int q4 = lane >> 4, l15 = lane & 15;
  const int len = lens[b];

  const unsigned short* Qp = Qw + (size_t)bh * T_ * D_;
  const unsigned short* Kp = Kw + (size_t)bh * T_ * D_;
  const unsigned short* Vp = Vt + (size_t)bh * D_ * T_;
  unsigned short* Pw = &Pb[w][0];

  const int ql0 = sl * 64 + w * 16;   // wave's 16 rows in low strip
  const int qh0 = sh * 64 + w * 16;   // wave's 16 rows in high strip

  // Q fragments for both groups (B-operand for swapped QK^T); lane l15 = q-row
  bf16x8 qfl[2], qfh[2];
#pragma unroll
  for (int kk = 0; kk < 2; ++kk) {
    qfl[kk] = *(const bf16x8*)(Qp + (size_t)(ql0 + l15) * D_ + kk * 32 + q4 * 8);
    qfh[kk] = *(const bf16x8*)(Qp + (size_t)(qh0 + l15) * D_ + kk * 32 + q4 * 8);
  }

  f32x4 otl[4] = {}, oth[4] = {};     // O^T accum per group
  float ml = -INFINITY, mh = -INFINITY;
  float lsl = 0.f, lsh = 0.f;

  int kcap = sh * 64 + 63;
  if (kcap > len - 1) kcap = len - 1;
  const int nkt = kcap / 64 + 1;      // covers high strip (superset of low)

  // staging: wave w stages rows w*16..w*16+15 of K and V tiles (2 calls each)
  const int srow = lane >> 3;   // 0..7
  const int scc = lane & 7;

  // prologue: stage tile 0 into buf 0
#pragma unroll
  for (int i = 0; i < 2; ++i) {
    int r0 = w * 16 + i * 8;
    int rk = r0 + srow;
    int kc = scc ^ (rk & 7);
    gload_lds16(Kp + (size_t)rk * D_ + kc * 8, &Ks[0][r0 * 64]);
    gload_lds16(Vp + (size_t)rk * T_ + kc * 8, &Vs[0][r0 * 64]);
  }
  __syncthreads();

  // per-group tile body (S^T -> softmax -> P -> O^T += V^T P^T)
  auto group_tile = [&](int kbase, int cur, int qg0, bf16x8 (&qf)[2],
                        f32x4 (&ot)[4], float& m, float& lsum) {
    // ---- S^T = K Q^T : st[nt], lane: col=q=l15, row=k=nt*16+q4*4+r
    f32x4 st[4];
#pragma unroll
    for (int nt = 0; nt < 4; ++nt) {
      bf16x8 kfr0, kfr1;
      {
        int row = nt * 16 + l15;
        int pc0 = q4 ^ (row & 7);
        int pc1 = (4 + q4) ^ (row & 7);
        kfr0 = *(const bf16x8*)(&Ks[cur][row * 64 + pc0 * 8]);
        kfr1 = *(const bf16x8*)(&Ks[cur][row * 64 + pc1 * 8]);
      }
      f32x4 z = {};
      z = __builtin_amdgcn_mfma_f32_16x16x32_bf16(kfr0, qf[0], z, 0, 0, 0);
      z = __builtin_amdgcn_mfma_f32_16x16x32_bf16(kfr1, qf[1], z, 0, 0, 0);
      st[nt] = z;
    }
    // ---- mask + per-row (per-lane) max
    const bool interior = (kbase + 63 <= qg0) && (kbase + 63 < len);
    float pmax = -INFINITY;
    if (interior) {
#pragma unroll
      for (int nt = 0; nt < 4; ++nt)
#pragma unroll
        for (int r = 0; r < 4; ++r) pmax = fmaxf(pmax, st[nt][r]);
    } else {
      const int qq = qg0 + l15;
#pragma unroll
      for (int nt = 0; nt < 4; ++nt)
#pragma unroll
        for (int r = 0; r < 4; ++r) {
          int kpos = kbase + nt * 16 + q4 * 4 + r;
          bool ok = (kpos < len) && (kpos <= qq);
          float v = ok ? st[nt][r] : -INFINITY;
          st[nt][r] = v;
          pmax = fmaxf(pmax, v);
        }
    }
    pmax = fmaxf(pmax, __shfl_xor(pmax, 16));
    pmax = fmaxf(pmax, __shfl_xor(pmax, 32));
    // ---- defer-max rescale (THR=8 in log2 domain)
    if (!__all(pmax <= m + 8.f)) {
      float mn = fmaxf(m, pmax);
      float sc = exp2f(m - mn);
      m = mn;
      lsum *= sc;
#pragma unroll
      for (int dt = 0; dt < 4; ++dt)
#pragma unroll
        for (int r = 0; r < 4; ++r) ot[dt][r] *= sc;
    }
    // ---- P = exp2(S - m): pack pairs, accumulate psum, write b64 to LDS
    float psum = 0.f;
#pragma unroll
    for (int nt = 0; nt < 4; ++nt) {
      float p0 = exp2f(st[nt][0] - m);
      float p1 = exp2f(st[nt][1] - m);
      float p2 = exp2f(st[nt][2] - m);
      float p3 = exp2f(st[nt][3] - m);
      psum += (p0 + p1) + (p2 + p3);
      uint32_t w0 = pack_bf16x2(p0, p1);
      uint32_t w1 = pack_bf16x2(p2, p3);
      int c = nt * 4 + q4;                    // 8B chunk (4 bf16), k=c*4
      int phys = c ^ ((l15 & 7) << 1);        // keeps pairs adjacent
      uint2 pr; pr.x = w0; pr.y = w1;
      *(uint2*)(&Pw[l15 * 64 + phys * 4]) = pr;
    }
    psum += __shfl_xor(psum, 16);
    psum += __shfl_xor(psum, 32);
    lsum += psum;
    // ---- PV: O^T += V^T P^T
    bf16x8 pt[2];
#pragma unroll
    for (int kk = 0; kk < 2; ++kk) {
      int c0 = kk * 8 + q4 * 2;               // even chunk, b128 = 2 chunks
      int phys = c0 ^ ((l15 & 7) << 1);
      pt[kk] = *(const bf16x8*)(&Pw[l15 * 64 + phys * 4]);
    }
#pragma unroll
    for (int dt = 0; dt < 4; ++dt) {
      bf16x8 vfr0, vfr1;
      {
        int row = dt * 16 + l15;
        int pc0 = q4 ^ (row & 7);
        int pc1 = (4 + q4) ^ (row & 7);
        vfr0 = *(const bf16x8*)(&Vs[cur][row * 64 + pc0 * 8]);
        vfr1 = *(const bf16x8*)(&Vs[cur][row * 64 + pc1 * 8]);
      }
      ot[dt] = __builtin_amdgcn_mfma_f32_16x16x32_bf16(vfr0, pt[0], ot[dt], 0, 0, 0);
      ot[dt] = __builtin_amdgcn_mfma_f32_16x16x32_bf16(vfr1, pt[1], ot[dt], 0, 0, 0);
    }
  };

  int cur = 0;
  for (int kt = 0; kt < nkt; ++kt) {
    const int kbase = kt * 64;
    // prefetch next tile into back buffer (in flight during compute)
    if (kt + 1 < nkt) {
      const int kb2 = kbase + 64;
#pragma unroll
      for (int i = 0; i < 2; ++i) {
        int r0 = w * 16 + i * 8;
        int rk = r0 + srow;
        int kc = scc ^ (rk & 7);
        gload_lds16(Kp + (size_t)(kb2 + rk) * D_ + kc * 8, &Ks[cur ^ 1][r0 * 64]);
        gload_lds16(Vp + (size_t)rk * T_ + kb2 + kc * 8, &Vs[cur ^ 1][r0 * 64]);
      }
    }

    // high strip computes every tile (kbase <= sh*64 <= qh0+15 always)
    group_tile(kbase, cur, qh0, qfh, oth, mh, lsh);
    // low strip active while kt <= sl (uniform across waves)
    if (kt <= sl) group_tile(kbase, cur, ql0, qfl, otl, ml, lsl);

    __syncthreads();   // drains prefetch (vmcnt0) + guards buffer reuse
    cur ^= 1;
  }

  // epilogue: O^T frag -> lane l15=q, d = dt*16 + q4*4 + r (4 consecutive)
  {
    float invl = 1.f / lsl;
    float invh = 1.f / lsh;
    int qql = ql0 + l15;
    int qqh = qh0 + l15;
#pragma unroll
    for (int dt = 0; dt < 4; ++dt) {
      uint2 pr;
      pr.x = pack_bf16x2(otl[dt][0] * invl, otl[dt][1] * invl);
      pr.y = pack_bf16x2(otl[dt][2] * invl, otl[dt][3] * invl);
      *(uint2*)(&AO[(size_t)(b * T_ + qql) * C_ + h * 64 + dt * 16 + q4 * 4]) = pr;
      uint2 ph;
      ph.x = pack_bf16x2(oth[dt][0] * invh, oth[dt][1] * invh);
      ph.y = pack_bf16x2(oth[dt][2] * invh, oth[dt][3] * invh);
      *(uint2*)(&AO[(size_t)(b * T_ + qqh) * C_ + h * 64 + dt * 16 + q4 * 4]) = ph;
    }
  }
}

// ---------------------------------------------------------------- launch
extern "C" void kernel_launch(void* const* d_in, const int* in_sizes, int n_in,
                              void* d_out, int out_size, void* d_ws, size_t ws_size,
                              hipStream_t stream) {
  const float* x = (const float*)d_in[0];
  const unsigned int* mask = (const unsigned int*)d_in[1];
  const float* Wqkv = (const float*)d_in[2];
  const float* bqkv = (const float*)d_in[3];
  const float* Wproj = (const float*)d_in[4];
  const float* bproj = (const float*)d_in[5];
  float* out = (float*)d_out;

  unsigned short* XB = (unsigned short*)d_ws;       // x bf16       (4096x1024)
  unsigned short* WQ = XB + 4194304;                // Wqkv bf16    (3072x1024)
  unsigned short* WP = WQ + 3145728;                // Wproj bf16   (1024x1024)
  unsigned short* Qw = WP + 1048576;                // (B,H,T,D)
  unsigned short* Kw = Qw + 4194304;
  unsigned short* Vw = Kw + 4194304;
  unsigned short* Vt = Vw + 4194304;                // (B,H,D,T)
  unsigned short* AO = Vt + 4194304;                // attn out (B,T,C) bf16
  int* lens = (int*)(AO + 4194304);

  cvt_all<<<8192, 256, 0, stream>>>(x, Wqkv, Wproj, XB, WQ, WP);
  compute_lengths<<<1, 64, 0, stream>>>(mask, lens);

  // QKV projection: M=4096, N=3072, K=1024, scatter epilogue
  gemm_bt<<<dim3(3072 / 128, 4096 / 128), 256, 0, stream>>>(
      XB, WQ, bqkv, nullptr, Qw, Kw, Vw, 3072, 1024, 0);

  transpose_v<<<dim3(T_ / 64, B_ * H_), 256, 0, stream>>>(Vw, Vt);

  attn_fwd<<<dim3(16, B_ * H_), 256, 0, stream>>>(Qw, Kw, Vt, AO, lens);

  // output projection: M=4096, N=1024, K=1024, fp32 out
  gemm_bt<<<dim3(1024 / 128, 4096 / 128), 256, 0, stream>>>(
      AO, WP, bproj, out, nullptr, nullptr, nullptr, 1024, 1024, 1);
}